// Round 3
// baseline (5589.154 us; speedup 1.0000x reference)
//
#include <hip/hip_runtime.h>
#include <hip/hip_bf16.h>

// QRNN: T=512, B=64, IN=512, H=1024, OUT=512. All inputs/outputs FP32
// (round-2 NaN = fp32 misread as bf16; reference file is jnp.float32).
// Pipeline: [gemm+act -> fo-scan] x chunks (layer0) -> same (layer1) -> fc.
// ws layout (adaptive):
//   h0: bf16 T*B*H    @ ws + 0      (64 MB)   intermediate, bf16 ok (2% thr)
//   h1: bf16 T*B*H    @ ws + 64MB   (64 MB)
//   g : fp32 T*B*3*CW @ ws + 128MB  (25..402 MB, CW in {64..1024})

#define QT 512
#define QB 64
#define QIN 512
#define QH 1024
#define QOUT 512

typedef unsigned short ushort_t;

__device__ __forceinline__ float u2f(ushort_t u) {
    union { unsigned int i; float f; } v;
    v.i = ((unsigned int)u) << 16;
    return v.f;
}

__device__ __forceinline__ ushort_t f2bf(float f) {
    union { float f; unsigned int i; } v;
    v.f = f;
    unsigned int r = v.i + 0x7fffu + ((v.i >> 16) & 1u);  // RNE
    return (ushort_t)(r >> 16);
}

__device__ __forceinline__ void load4(const float* p, float v[4]) {
    float4 t = *(const float4*)p;
    v[0] = t.x; v[1] = t.y; v[2] = t.z; v[3] = t.w;
}
__device__ __forceinline__ void load4(const ushort_t* p, float v[4]) {
    ushort4 t = *(const ushort4*)p;
    v[0] = u2f(t.x); v[1] = u2f(t.y); v[2] = u2f(t.z); v[3] = u2f(t.w);
}

// ---------------------------------------------------------------------------
// Tiled GEMM over a gate-chunk. A: AT (float or bf16), W/bias: fp32.
// MODE 0: out = fp32 g-chunk (M x 3*CW), act = tanh (gate 0) / sigmoid (1,2).
//         W row stride 3*QH; block column wn0 = gate*QH + c0 + local*64.
// MODE 1: FC. out = fp32 (M x QOUT), bias only; c0/CW unused.
// BM=BN=64, BK=16, 256 threads, 4x4 micro-tile, fp32 accumulate.
// ---------------------------------------------------------------------------
template <int MODE, typename AT>
__global__ __launch_bounds__(256) void gemm_act(
    const AT* __restrict__ A, const float* __restrict__ W,
    const float* __restrict__ bias, float* __restrict__ out,
    int K, int c0, int CW) {
    __shared__ float As[16][68];  // [k][m]
    __shared__ float Bs[16][68];  // [k][n]

    const int tid = threadIdx.x;
    const int tx = tid & 15;
    const int ty = tid >> 4;
    const int m0 = blockIdx.y * 64;

    int wn0, gn0, outstride;
    bool use_tanh = false;
    const int Wstride = (MODE == 0) ? 3 * QH : QOUT;
    if (MODE == 0) {
        const int per = CW >> 6;  // 64-col blocks per gate
        const int gate = blockIdx.x / per;
        const int local = blockIdx.x - gate * per;
        wn0 = gate * QH + c0 + local * 64;
        gn0 = gate * CW + local * 64;
        outstride = 3 * CW;
        use_tanh = (gate == 0);
    } else {
        wn0 = blockIdx.x * 64;
        gn0 = wn0;
        outstride = QOUT;
    }

    // A-tile: 64 rows x 16 cols, 4 elems/thread. W-tile: 16 rows x 64 cols.
    const int ar = tid >> 2;
    const int ac = (tid & 3) * 4;
    const int br = tid >> 4;
    const int bc = (tid & 15) * 4;

    float acc[4][4] = {};

    for (int k0 = 0; k0 < K; k0 += 16) {
        float av[4], bv[4];
        load4(A + (size_t)(m0 + ar) * K + k0 + ac, av);
        load4(W + (size_t)(k0 + br) * Wstride + wn0 + bc, bv);
        __syncthreads();
        As[ac + 0][ar] = av[0];
        As[ac + 1][ar] = av[1];
        As[ac + 2][ar] = av[2];
        As[ac + 3][ar] = av[3];
        *(float4*)&Bs[br][bc] = make_float4(bv[0], bv[1], bv[2], bv[3]);
        __syncthreads();
#pragma unroll
        for (int kk = 0; kk < 16; ++kk) {
            float4 a = *(const float4*)&As[kk][ty * 4];
            float4 b = *(const float4*)&Bs[kk][tx * 4];
            float ai[4] = {a.x, a.y, a.z, a.w};
            float bj[4] = {b.x, b.y, b.z, b.w};
#pragma unroll
            for (int i = 0; i < 4; ++i)
#pragma unroll
                for (int j = 0; j < 4; ++j) acc[i][j] += ai[i] * bj[j];
        }
    }

#pragma unroll
    for (int i = 0; i < 4; ++i) {
        const int m = m0 + ty * 4 + i;
        float v[4];
#pragma unroll
        for (int j = 0; j < 4; ++j) {
            float xv = acc[i][j] + bias[wn0 + tx * 4 + j];
            v[j] = (MODE == 0)
                       ? (use_tanh ? tanhf(xv) : 1.f / (1.f + expf(-xv)))
                       : xv;
        }
        *(float4*)&out[(size_t)m * outstride + gn0 + tx * 4] =
            make_float4(v[0], v[1], v[2], v[3]);
    }
}

// ---------------------------------------------------------------------------
// fo-pool scan over one gate-chunk. g: (T, B, 3, CW) fp32 activated z,f,o.
// h[t, b, c0+hh] = o * c with c = f*c + (1-f)*z. One thread per (b, hh).
// ---------------------------------------------------------------------------
__global__ __launch_bounds__(256) void fo_scan(const float* __restrict__ g,
                                               ushort_t* __restrict__ h,
                                               int c0, int CW) {
    const int idx = blockIdx.x * blockDim.x + threadIdx.x;  // b*CW + hh
    const int b = idx / CW;
    const int hh = idx - b * CW;
    const float* gp = g + (size_t)b * 3 * CW + hh;
    ushort_t* hp = h + (size_t)b * QH + c0 + hh;
    const size_t grow = (size_t)QB * 3 * CW;
    const size_t hrow = (size_t)QB * QH;
    float c = 0.f;
    for (int t = 0; t < QT; ++t) {
        float z = gp[0];
        float f = gp[CW];
        float o = gp[2 * CW];
        c = f * c + (1.f - f) * z;
        *hp = f2bf(o * c);
        gp += grow;
        hp += hrow;
    }
}

extern "C" void kernel_launch(void* const* d_in, const int* in_sizes, int n_in,
                              void* d_out, int out_size, void* d_ws,
                              size_t ws_size, hipStream_t stream) {
    const float* x   = (const float*)d_in[0];
    const float* W0  = (const float*)d_in[1];
    const float* b0  = (const float*)d_in[2];
    const float* W1  = (const float*)d_in[3];
    const float* b1  = (const float*)d_in[4];
    const float* Wfc = (const float*)d_in[5];
    const float* bfc = (const float*)d_in[6];
    float* out = (float*)d_out;

    const int M = QT * QB;  // 32768
    ushort_t* h0 = (ushort_t*)d_ws;
    ushort_t* h1 = h0 + (size_t)M * QH;
    const size_t base = 2 * (size_t)M * QH * sizeof(ushort_t);  // 128 MB
    float* g = (float*)((char*)d_ws + base);

    // Largest gate-chunk width that fits the workspace.
    int CW = QH;
    while (CW > 64 && base + (size_t)M * 3 * CW * sizeof(float) > ws_size)
        CW >>= 1;
    const int nch = QH / CW;

    dim3 blk(256);
    const dim3 ggrid(3 * (CW >> 6), M / 64);
    const dim3 sgrid(QB * CW / 256);

    for (int ci = 0; ci < nch; ++ci) {
        gemm_act<0, float><<<ggrid, blk, 0, stream>>>(x, W0, b0, g, QIN,
                                                      ci * CW, CW);
        fo_scan<<<sgrid, blk, 0, stream>>>(g, h0, ci * CW, CW);
    }
    for (int ci = 0; ci < nch; ++ci) {
        gemm_act<0, ushort_t><<<ggrid, blk, 0, stream>>>(h0, W1, b1, g, QH,
                                                         ci * CW, CW);
        fo_scan<<<sgrid, blk, 0, stream>>>(g, h1, ci * CW, CW);
    }
    gemm_act<1, ushort_t><<<dim3(QOUT / 64, M / 64), blk, 0, stream>>>(
        h1, Wfc, bfc, out, QH, 0, 0);
}

// Round 4
// 3073.183 us; speedup vs baseline: 1.8187x; 1.8187x over previous
//
#include <hip/hip_runtime.h>
#include <hip/hip_bf16.h>

// QRNN: T=512, B=64, IN=512, H=1024, OUT=512. fp32 in/out.
// R4: bf16 MFMA GEMMs (16x16x32), 128x128x64 tiles, global_load_lds staging,
// XOR-swizzled LDS. Pre-pass: x -> bf16, W* -> bf16 transposed (N x K).
// ws layout:
//   h0  : bf16 QM*QH    @ 0        (64 MiB)
//   h1  : bf16 QM*QH    @ 64 MiB   (64 MiB)
//   x_bf: bf16 QM*QIN   @ 128 MiB  (32 MiB)
//   W0T : bf16 3QH*QIN  @ 160 MiB  (3 MiB)
//   W1T : bf16 3QH*QH   @ 163 MiB  (6 MiB)
//   WfcT: bf16 QOUT*QH  @ 169 MiB  (1 MiB)
//   g   : fp32 QM*3*CW  @ 170 MiB  (48..384 MiB, CW adaptive >=128)

#define QT 512
#define QB 64
#define QIN 512
#define QH 1024
#define QOUT 512
#define QM (QT * QB)

typedef unsigned short ushort_t;
typedef __attribute__((ext_vector_type(8))) short bf16x8;
typedef __attribute__((ext_vector_type(4))) float f32x4;

__device__ __forceinline__ ushort_t f2bf(float f) {
    union { float f; unsigned int i; } v;
    v.f = f;
    unsigned int r = v.i + 0x7fffu + ((v.i >> 16) & 1u);  // RNE
    return (ushort_t)(r >> 16);
}

__device__ __forceinline__ void glds16(const ushort_t* g, ushort_t* l) {
    __builtin_amdgcn_global_load_lds(
        (const __attribute__((address_space(1))) void*)g,
        (__attribute__((address_space(3))) void*)l, 16, 0, 0);
}

// --------------------------- pre-pass kernels ------------------------------
__global__ __launch_bounds__(256) void cvt_bf16(const float* __restrict__ src,
                                                ushort_t* __restrict__ dst) {
    const int i = blockIdx.x * 256 + threadIdx.x;
    float4 v = ((const float4*)src)[i];
    ushort4 o;
    o.x = f2bf(v.x); o.y = f2bf(v.y); o.z = f2bf(v.z); o.w = f2bf(v.w);
    ((ushort4*)dst)[i] = o;
}

// W (K x N fp32) -> WT (N x K bf16)
__global__ __launch_bounds__(256) void transpose_cvt(
    const float* __restrict__ W, ushort_t* __restrict__ WT, int K, int N) {
    __shared__ float t[32][33];
    const int tx = threadIdx.x & 31, ty = threadIdx.x >> 5;
    const int n0 = blockIdx.x * 32, k0 = blockIdx.y * 32;
#pragma unroll
    for (int i = 0; i < 4; ++i)
        t[ty + 8 * i][tx] = W[(size_t)(k0 + ty + 8 * i) * N + n0 + tx];
    __syncthreads();
#pragma unroll
    for (int i = 0; i < 4; ++i)
        WT[(size_t)(n0 + ty + 8 * i) * K + k0 + tx] = f2bf(t[tx][ty + 8 * i]);
}

// ------------------------------ MFMA GEMM ----------------------------------
// C = A(M x K, bf16 row-major) @ BT(N x K, bf16 row-major)^T.
// MODE 0: out fp32 g-chunk (M x 3*CW), tanh (gate 0) / sigmoid (gates 1,2),
//         BT rows = gate*QH + c0 + local. MODE 1: FC, bias only.
// Block: 256 thr = 4 waves, tile 128x128, BK=64. Wave quadrant 64x64.
// LDS granule (row m, kg) stored at slot m*8 + (kg ^ (m&7))  [16B granules].
template <int MODE>
__global__ __launch_bounds__(256) void gemm_mfma(
    const ushort_t* __restrict__ A, const ushort_t* __restrict__ BT,
    const float* __restrict__ bias, float* __restrict__ out,
    int K, int c0, int CW) {
    __shared__ ushort_t As[128 * 64];
    __shared__ ushort_t Bs[128 * 64];

    const int tid = threadIdx.x;
    const int lane = tid & 63;
    const int w = tid >> 6;
    const int wr = w >> 1, wc = w & 1;
    const int m0 = blockIdx.y * 128;

    int nW, nOut, outstride, gate = 0;
    if (MODE == 0) {
        const int per = CW >> 7;  // 128-col blocks per gate
        gate = blockIdx.x / per;
        const int nloc = (blockIdx.x - gate * per) * 128;
        nW = gate * QH + c0 + nloc;   // row base in WT / bias col base
        nOut = gate * CW + nloc;      // col base in g-chunk
        outstride = 3 * CW;
    } else {
        nW = blockIdx.x * 128;
        nOut = nW;
        outstride = QOUT;
    }

    // Staging: slot s = (w*4+j)*64 + lane; granule row ms = s>>3,
    // stored kg' = s&7 -> global kg = (s&7) ^ (ms&7). 8 lanes cover one
    // 128B line (permuted within the line -> still one transaction).
    size_t aoff[4], boff[4];
    int soff[4];
#pragma unroll
    for (int j = 0; j < 4; ++j) {
        const int s = ((w * 4 + j) << 6) + lane;
        const int ms = s >> 3;
        const int kg = (s & 7) ^ (ms & 7);
        aoff[j] = (size_t)(m0 + ms) * K + kg * 8;
        boff[j] = (size_t)(nW + ms) * K + kg * 8;
        soff[j] = (w * 4 + j) << 9;  // wave-uniform LDS base (elements)
    }

    // Fragment LDS element offsets (A[m=lane&15][k=(lane>>4)*8+j] layout).
    const int fl = lane & 15, fq = lane >> 4, l7 = lane & 7;
    int aidx[2][4], bidx[2][4];
#pragma unroll
    for (int ks = 0; ks < 2; ++ks)
#pragma unroll
        for (int i = 0; i < 4; ++i) {
            const int am = wr * 64 + i * 16 + fl;
            const int bn = wc * 64 + i * 16 + fl;
            const int kq = ks * 4 + fq;
            aidx[ks][i] = (am * 8 + (kq ^ l7)) * 8;
            bidx[ks][i] = (bn * 8 + (kq ^ l7)) * 8;
        }

    f32x4 acc[4][4];
#pragma unroll
    for (int i = 0; i < 4; ++i)
#pragma unroll
        for (int j = 0; j < 4; ++j) acc[i][j] = {0.f, 0.f, 0.f, 0.f};

    for (int k0 = 0; k0 < K; k0 += 64) {
        __syncthreads();
#pragma unroll
        for (int j = 0; j < 4; ++j) glds16(A + aoff[j] + k0, &As[soff[j]]);
#pragma unroll
        for (int j = 0; j < 4; ++j) glds16(BT + boff[j] + k0, &Bs[soff[j]]);
        __syncthreads();
#pragma unroll
        for (int ks = 0; ks < 2; ++ks) {
            bf16x8 af[4], bv[4];
#pragma unroll
            for (int i = 0; i < 4; ++i)
                af[i] = *(const bf16x8*)&As[aidx[ks][i]];
#pragma unroll
            for (int j = 0; j < 4; ++j)
                bv[j] = *(const bf16x8*)&Bs[bidx[ks][j]];
#pragma unroll
            for (int i = 0; i < 4; ++i)
#pragma unroll
                for (int j = 0; j < 4; ++j)
                    acc[i][j] = __builtin_amdgcn_mfma_f32_16x16x32_bf16(
                        af[i], bv[j], acc[i][j], 0, 0, 0);
        }
    }

    // Epilogue. C/D: col = lane&15, row = (lane>>4)*4 + reg.
    const int rbase = fq * 4;
#pragma unroll
    for (int i = 0; i < 4; ++i) {
#pragma unroll
        for (int j = 0; j < 4; ++j) {
            const int col = nOut + wc * 64 + j * 16 + fl;
            const float bvv = bias[nW + wc * 64 + j * 16 + fl];
            const int row0 = m0 + wr * 64 + i * 16 + rbase;
#pragma unroll
            for (int r = 0; r < 4; ++r) {
                float v = acc[i][j][r] + bvv;
                if (MODE == 0)
                    v = (gate == 0) ? tanhf(v) : 1.f / (1.f + expf(-v));
                out[(size_t)(row0 + r) * outstride + col] = v;
            }
        }
    }
}

// ------------------------------- fo-scan -----------------------------------
__global__ __launch_bounds__(256) void fo_scan(const float* __restrict__ g,
                                               ushort_t* __restrict__ h,
                                               int c0, int CW) {
    const int idx = blockIdx.x * blockDim.x + threadIdx.x;  // b*CW + hh
    const int b = idx / CW;
    const int hh = idx - b * CW;
    const float* gp = g + (size_t)b * 3 * CW + hh;
    ushort_t* hp = h + (size_t)b * QH + c0 + hh;
    const size_t grow = (size_t)QB * 3 * CW;
    const size_t hrow = (size_t)QB * QH;
    float c = 0.f;
    for (int t = 0; t < QT; ++t) {
        float z = gp[0];
        float f = gp[CW];
        float o = gp[2 * CW];
        c = f * c + (1.f - f) * z;
        *hp = f2bf(o * c);
        gp += grow;
        hp += hrow;
    }
}

extern "C" void kernel_launch(void* const* d_in, const int* in_sizes, int n_in,
                              void* d_out, int out_size, void* d_ws,
                              size_t ws_size, hipStream_t stream) {
    const float* x   = (const float*)d_in[0];
    const float* W0  = (const float*)d_in[1];
    const float* b0  = (const float*)d_in[2];
    const float* W1  = (const float*)d_in[3];
    const float* b1  = (const float*)d_in[4];
    const float* Wfc = (const float*)d_in[5];
    const float* bfc = (const float*)d_in[6];
    float* out = (float*)d_out;

    char* p = (char*)d_ws;
    ushort_t* h0   = (ushort_t*)p;                      p += (size_t)QM * QH * 2;
    ushort_t* h1   = (ushort_t*)p;                      p += (size_t)QM * QH * 2;
    ushort_t* x_bf = (ushort_t*)p;                      p += (size_t)QM * QIN * 2;
    ushort_t* W0T  = (ushort_t*)p;                      p += (size_t)3 * QH * QIN * 2;
    ushort_t* W1T  = (ushort_t*)p;                      p += (size_t)3 * QH * QH * 2;
    ushort_t* WfcT = (ushort_t*)p;                      p += (size_t)QOUT * QH * 2;
    const size_t base = (size_t)(p - (char*)d_ws);
    float* g = (float*)p;

    // Largest gate-chunk width that fits (>=128 for the 128-wide GEMM tile).
    int CW = QH;
    while (CW > 128 && base + (size_t)QM * 3 * CW * 4 > ws_size) CW >>= 1;
    const int nch = QH / CW;

    dim3 blk(256);

    // Pre-pass: convert + transpose.
    cvt_bf16<<<dim3(QM * QIN / 1024), blk, 0, stream>>>(x, x_bf);
    transpose_cvt<<<dim3(3 * QH / 32, QIN / 32), blk, 0, stream>>>(
        W0, W0T, QIN, 3 * QH);
    transpose_cvt<<<dim3(3 * QH / 32, QH / 32), blk, 0, stream>>>(
        W1, W1T, QH, 3 * QH);
    transpose_cvt<<<dim3(QOUT / 32, QH / 32), blk, 0, stream>>>(
        Wfc, WfcT, QH, QOUT);

    const dim3 ggrid(3 * (CW >> 7), QM / 128);
    const dim3 sgrid(QB * CW / 256);

    for (int ci = 0; ci < nch; ++ci) {
        gemm_mfma<0><<<ggrid, blk, 0, stream>>>(x_bf, W0T, b0, g, QIN,
                                                ci * CW, CW);
        fo_scan<<<sgrid, blk, 0, stream>>>(g, h0, ci * CW, CW);
    }
    for (int ci = 0; ci < nch; ++ci) {
        gemm_mfma<0><<<ggrid, blk, 0, stream>>>(h0, W1T, b1, g, QH,
                                                ci * CW, CW);
        fo_scan<<<sgrid, blk, 0, stream>>>(g, h1, ci * CW, CW);
    }
    gemm_mfma<1><<<dim3(QOUT / 128, QM / 128), blk, 0, stream>>>(
        h1, WfcT, bfc, out, QH, 0, 0);
}

// Round 5
// 1104.625 us; speedup vs baseline: 5.0598x; 2.7821x over previous
//
#include <hip/hip_runtime.h>
#include <hip/hip_bf16.h>

// QRNN: T=512, B=64, IN=512, H=1024, OUT=512. fp32 in/out.
// R5: segmented parallel fo-scan (32 segments x 16 steps, 3 passes) replaces
// the 512-step latency-chain scan. GEMM: bf16 MFMA 128x128x64 (unchanged).
// ws layout:
//   h0  : bf16 QM*QH    (64 MiB)
//   h1  : bf16 QM*QH    (64 MiB)
//   x_bf: bf16 QM*QIN   (32 MiB)
//   W0T : bf16 3QH*QIN  (3 MiB)
//   W1T : bf16 3QH*QH   (6 MiB)
//   WfcT: bf16 QOUT*QH  (1 MiB)
//   Aseg/Bseg/cstart: fp32 QB*CW*SEG each (2 MiB ea @ CW=256)
//   g   : fp32 QM*3*CW  (48..384 MiB, CW adaptive >=128)

#define QT 512
#define QB 64
#define QIN 512
#define QH 1024
#define QOUT 512
#define QM (QT * QB)
#define SEG 32
#define SL (QT / SEG)  // 16

typedef unsigned short ushort_t;
typedef __attribute__((ext_vector_type(8))) short bf16x8;
typedef __attribute__((ext_vector_type(4))) float f32x4;

__device__ __forceinline__ ushort_t f2bf(float f) {
    union { float f; unsigned int i; } v;
    v.f = f;
    unsigned int r = v.i + 0x7fffu + ((v.i >> 16) & 1u);  // RNE
    return (ushort_t)(r >> 16);
}

__device__ __forceinline__ void glds16(const ushort_t* g, ushort_t* l) {
    __builtin_amdgcn_global_load_lds(
        (const __attribute__((address_space(1))) void*)g,
        (__attribute__((address_space(3))) void*)l, 16, 0, 0);
}

// --------------------------- pre-pass kernels ------------------------------
__global__ __launch_bounds__(256) void cvt_bf16(const float* __restrict__ src,
                                                ushort_t* __restrict__ dst) {
    const int i = blockIdx.x * 256 + threadIdx.x;
    float4 v = ((const float4*)src)[i];
    ushort4 o;
    o.x = f2bf(v.x); o.y = f2bf(v.y); o.z = f2bf(v.z); o.w = f2bf(v.w);
    ((ushort4*)dst)[i] = o;
}

// W (K x N fp32) -> WT (N x K bf16)
__global__ __launch_bounds__(256) void transpose_cvt(
    const float* __restrict__ W, ushort_t* __restrict__ WT, int K, int N) {
    __shared__ float t[32][33];
    const int tx = threadIdx.x & 31, ty = threadIdx.x >> 5;
    const int n0 = blockIdx.x * 32, k0 = blockIdx.y * 32;
#pragma unroll
    for (int i = 0; i < 4; ++i)
        t[ty + 8 * i][tx] = W[(size_t)(k0 + ty + 8 * i) * N + n0 + tx];
    __syncthreads();
#pragma unroll
    for (int i = 0; i < 4; ++i)
        WT[(size_t)(n0 + ty + 8 * i) * K + k0 + tx] = f2bf(t[tx][ty + 8 * i]);
}

// ------------------------------ MFMA GEMM ----------------------------------
// C = A(M x K, bf16 row-major) @ BT(N x K, bf16 row-major)^T.
// MODE 0: out fp32 g-chunk (M x 3*CW), tanh (gate 0) / sigmoid (gates 1,2).
// MODE 1: FC, bias only. 256 thr = 4 waves, tile 128x128, BK=64.
template <int MODE>
__global__ __launch_bounds__(256) void gemm_mfma(
    const ushort_t* __restrict__ A, const ushort_t* __restrict__ BT,
    const float* __restrict__ bias, float* __restrict__ out,
    int K, int c0, int CW) {
    __shared__ ushort_t As[128 * 64];
    __shared__ ushort_t Bs[128 * 64];

    const int tid = threadIdx.x;
    const int lane = tid & 63;
    const int w = tid >> 6;
    const int wr = w >> 1, wc = w & 1;
    const int m0 = blockIdx.y * 128;

    int nW, nOut, outstride, gate = 0;
    if (MODE == 0) {
        const int per = CW >> 7;
        gate = blockIdx.x / per;
        const int nloc = (blockIdx.x - gate * per) * 128;
        nW = gate * QH + c0 + nloc;
        nOut = gate * CW + nloc;
        outstride = 3 * CW;
    } else {
        nW = blockIdx.x * 128;
        nOut = nW;
        outstride = QOUT;
    }

    size_t aoff[4], boff[4];
    int soff[4];
#pragma unroll
    for (int j = 0; j < 4; ++j) {
        const int s = ((w * 4 + j) << 6) + lane;
        const int ms = s >> 3;
        const int kg = (s & 7) ^ (ms & 7);
        aoff[j] = (size_t)(m0 + ms) * K + kg * 8;
        boff[j] = (size_t)(nW + ms) * K + kg * 8;
        soff[j] = (w * 4 + j) << 9;
    }

    const int fl = lane & 15, fq = lane >> 4, l7 = lane & 7;
    int aidx[2][4], bidx[2][4];
#pragma unroll
    for (int ks = 0; ks < 2; ++ks)
#pragma unroll
        for (int i = 0; i < 4; ++i) {
            const int am = wr * 64 + i * 16 + fl;
            const int bn = wc * 64 + i * 16 + fl;
            const int kq = ks * 4 + fq;
            aidx[ks][i] = (am * 8 + (kq ^ l7)) * 8;
            bidx[ks][i] = (bn * 8 + (kq ^ l7)) * 8;
        }

    f32x4 acc[4][4];
#pragma unroll
    for (int i = 0; i < 4; ++i)
#pragma unroll
        for (int j = 0; j < 4; ++j) acc[i][j] = {0.f, 0.f, 0.f, 0.f};

    for (int k0 = 0; k0 < K; k0 += 64) {
        __syncthreads();
#pragma unroll
        for (int j = 0; j < 4; ++j) glds16(A + aoff[j] + k0, &As[soff[j]]);
#pragma unroll
        for (int j = 0; j < 4; ++j) glds16(BT + boff[j] + k0, &Bs[soff[j]]);
        __syncthreads();
#pragma unroll
        for (int ks = 0; ks < 2; ++ks) {
            bf16x8 af[4], bv[4];
#pragma unroll
            for (int i = 0; i < 4; ++i)
                af[i] = *(const bf16x8*)&As[aidx[ks][i]];
#pragma unroll
            for (int j = 0; j < 4; ++j)
                bv[j] = *(const bf16x8*)&Bs[bidx[ks][j]];
#pragma unroll
            for (int i = 0; i < 4; ++i)
#pragma unroll
                for (int j = 0; j < 4; ++j)
                    acc[i][j] = __builtin_amdgcn_mfma_f32_16x16x32_bf16(
                        af[i], bv[j], acc[i][j], 0, 0, 0);
        }
    }

    const int rbase = fq * 4;
#pragma unroll
    for (int i = 0; i < 4; ++i) {
#pragma unroll
        for (int j = 0; j < 4; ++j) {
            const int col = nOut + wc * 64 + j * 16 + fl;
            const float bvv = bias[nW + wc * 64 + j * 16 + fl];
            const int row0 = m0 + wr * 64 + i * 16 + rbase;
#pragma unroll
            for (int r = 0; r < 4; ++r) {
                float v = acc[i][j][r] + bvv;
                if (MODE == 0)
                    v = (gate == 0) ? tanhf(v) : 1.f / (1.f + expf(-v));
                out[(size_t)(row0 + r) * outstride + col] = v;
            }
        }
    }
}

// ----------------------- segmented fo-scan (3 passes) ----------------------
// g: (T, B, 3, CW) fp32 activated z,f,o.
// Recurrence c=f*c+(1-f)*z composed as (A,B): c_out = A*c_in + B.

// Pass 1: per-(seg,b,hh) segment summary. idx = (s*QB + b)*CW + hh.
__global__ __launch_bounds__(256) void scan_p1(const float* __restrict__ g,
                                               float* __restrict__ Aseg,
                                               float* __restrict__ Bseg,
                                               int CW) {
    const int idx = blockIdx.x * 256 + threadIdx.x;
    const int hh = idx % CW;
    const int sb = idx / CW;
    const int b = sb % QB;
    const int s = sb / QB;
    const float* gp = g + ((size_t)(s * SL * QB + b) * 3) * CW + hh;
    const size_t grow = (size_t)QB * 3 * CW;
    float A = 1.f, Bc = 0.f;
#pragma unroll
    for (int t = 0; t < SL; ++t) {
        float z = gp[0];
        float f = gp[CW];
        Bc = f * Bc + (1.f - f) * z;
        A *= f;
        gp += grow;
    }
    Aseg[idx] = A;
    Bseg[idx] = Bc;
}

// Pass 2: scan the 32 segment summaries. idx = b*CW + hh.
__global__ __launch_bounds__(256) void scan_p2(const float* __restrict__ Aseg,
                                               const float* __restrict__ Bseg,
                                               float* __restrict__ cstart,
                                               int CW) {
    const int idx = blockIdx.x * 256 + threadIdx.x;
    const size_t stride = (size_t)QB * CW;
    float c = 0.f;
#pragma unroll
    for (int s = 0; s < SEG; ++s) {
        cstart[s * stride + idx] = c;
        c = Aseg[s * stride + idx] * c + Bseg[s * stride + idx];
    }
}

// Pass 3: recompute interior states, write h (bf16). Same map as pass 1.
__global__ __launch_bounds__(256) void scan_p3(const float* __restrict__ g,
                                               const float* __restrict__ cstart,
                                               ushort_t* __restrict__ h,
                                               int c0, int CW) {
    const int idx = blockIdx.x * 256 + threadIdx.x;
    const int hh = idx % CW;
    const int sb = idx / CW;
    const int b = sb % QB;
    const int s = sb / QB;
    const float* gp = g + ((size_t)(s * SL * QB + b) * 3) * CW + hh;
    ushort_t* hp = h + (size_t)(s * SL * QB + b) * QH + c0 + hh;
    const size_t grow = (size_t)QB * 3 * CW;
    const size_t hrow = (size_t)QB * QH;
    float c = cstart[idx];
#pragma unroll
    for (int t = 0; t < SL; ++t) {
        float z = gp[0];
        float f = gp[CW];
        float o = gp[2 * CW];
        c = f * c + (1.f - f) * z;
        *hp = f2bf(o * c);
        gp += grow;
        hp += hrow;
    }
}

extern "C" void kernel_launch(void* const* d_in, const int* in_sizes, int n_in,
                              void* d_out, int out_size, void* d_ws,
                              size_t ws_size, hipStream_t stream) {
    const float* x   = (const float*)d_in[0];
    const float* W0  = (const float*)d_in[1];
    const float* b0  = (const float*)d_in[2];
    const float* W1  = (const float*)d_in[3];
    const float* b1  = (const float*)d_in[4];
    const float* Wfc = (const float*)d_in[5];
    const float* bfc = (const float*)d_in[6];
    float* out = (float*)d_out;

    char* p = (char*)d_ws;
    ushort_t* h0   = (ushort_t*)p;  p += (size_t)QM * QH * 2;
    ushort_t* h1   = (ushort_t*)p;  p += (size_t)QM * QH * 2;
    ushort_t* x_bf = (ushort_t*)p;  p += (size_t)QM * QIN * 2;
    ushort_t* W0T  = (ushort_t*)p;  p += (size_t)3 * QH * QIN * 2;
    ushort_t* W1T  = (ushort_t*)p;  p += (size_t)3 * QH * QH * 2;
    ushort_t* WfcT = (ushort_t*)p;  p += (size_t)QOUT * QH * 2;
    const size_t base = (size_t)(p - (char*)d_ws);

    // Pick largest CW (>=128) fitting: base + summaries + g-chunk.
    int CW = QH;
    while (CW > 128 &&
           base + 3 * (size_t)QB * CW * SEG * 4 + (size_t)QM * 3 * CW * 4 >
               ws_size)
        CW >>= 1;
    const int nch = QH / CW;

    float* Aseg   = (float*)p;              p += (size_t)QB * CW * SEG * 4;
    float* Bseg   = (float*)p;              p += (size_t)QB * CW * SEG * 4;
    float* cstart = (float*)p;              p += (size_t)QB * CW * SEG * 4;
    float* g      = (float*)p;

    dim3 blk(256);

    cvt_bf16<<<dim3(QM * QIN / 1024), blk, 0, stream>>>(x, x_bf);
    transpose_cvt<<<dim3(3 * QH / 32, QIN / 32), blk, 0, stream>>>(
        W0, W0T, QIN, 3 * QH);
    transpose_cvt<<<dim3(3 * QH / 32, QH / 32), blk, 0, stream>>>(
        W1, W1T, QH, 3 * QH);
    transpose_cvt<<<dim3(QOUT / 32, QH / 32), blk, 0, stream>>>(
        Wfc, WfcT, QH, QOUT);

    const dim3 ggrid(3 * (CW >> 7), QM / 128);
    const dim3 p13grid(SEG * QB * CW / 256);
    const dim3 p2grid(QB * CW / 256);

    for (int ci = 0; ci < nch; ++ci) {
        gemm_mfma<0><<<ggrid, blk, 0, stream>>>(x_bf, W0T, b0, g, QIN,
                                                ci * CW, CW);
        scan_p1<<<p13grid, blk, 0, stream>>>(g, Aseg, Bseg, CW);
        scan_p2<<<p2grid, blk, 0, stream>>>(Aseg, Bseg, cstart, CW);
        scan_p3<<<p13grid, blk, 0, stream>>>(g, cstart, h0, ci * CW, CW);
    }
    for (int ci = 0; ci < nch; ++ci) {
        gemm_mfma<0><<<ggrid, blk, 0, stream>>>(h0, W1T, b1, g, QH,
                                                ci * CW, CW);
        scan_p1<<<p13grid, blk, 0, stream>>>(g, Aseg, Bseg, CW);
        scan_p2<<<p2grid, blk, 0, stream>>>(Aseg, Bseg, cstart, CW);
        scan_p3<<<p13grid, blk, 0, stream>>>(g, cstart, h1, ci * CW, CW);
    }
    gemm_mfma<1><<<dim3(QOUT / 128, QM / 128), blk, 0, stream>>>(
        h1, WfcT, bfc, out, QH, 0, 0);
}

// Round 6
// 792.759 us; speedup vs baseline: 7.0503x; 1.3934x over previous
//
#include <hip/hip_runtime.h>
#include <hip/hip_bf16.h>

// QRNN: T=512, B=64, IN=512, H=1024, OUT=512. fp32 in/out.
// R6: bf16 g (halves gate traffic), x_bf aliased into h1, CW=256 chunks
// (2x FLOP/A-byte vs R5's CW=128), register-chain scan_p2.
// ws layout (CW=256 => 192 MiB total):
//   h0  : bf16 QM*QH          (64 MiB)
//   h1  : bf16 QM*QH          (64 MiB; x_bf bf16 QM*QIN aliased in first 32)
//   W0T : bf16 3QH*QIN        (3 MiB)
//   W1T : bf16 3QH*QH         (6 MiB)
//   WfcT: bf16 QOUT*QH        (1 MiB)
//   Aseg/Bseg/cstart: fp32 QB*CW*SEG each
//   g   : bf16 QM*3*CW

#define QT 512
#define QB 64
#define QIN 512
#define QH 1024
#define QOUT 512
#define QM (QT * QB)
#define SEG 32
#define SL (QT / SEG)  // 16

typedef unsigned short ushort_t;
typedef __attribute__((ext_vector_type(8))) short bf16x8;
typedef __attribute__((ext_vector_type(4))) float f32x4;

__device__ __forceinline__ float u2f(ushort_t u) {
    union { unsigned int i; float f; } v;
    v.i = ((unsigned int)u) << 16;
    return v.f;
}

__device__ __forceinline__ ushort_t f2bf(float f) {
    union { float f; unsigned int i; } v;
    v.f = f;
    unsigned int r = v.i + 0x7fffu + ((v.i >> 16) & 1u);  // RNE
    return (ushort_t)(r >> 16);
}

__device__ __forceinline__ void glds16(const ushort_t* g, ushort_t* l) {
    __builtin_amdgcn_global_load_lds(
        (const __attribute__((address_space(1))) void*)g,
        (__attribute__((address_space(3))) void*)l, 16, 0, 0);
}

// --------------------------- pre-pass kernels ------------------------------
__global__ __launch_bounds__(256) void cvt_bf16(const float* __restrict__ src,
                                                ushort_t* __restrict__ dst) {
    const int i = blockIdx.x * 256 + threadIdx.x;
    float4 v = ((const float4*)src)[i];
    ushort4 o;
    o.x = f2bf(v.x); o.y = f2bf(v.y); o.z = f2bf(v.z); o.w = f2bf(v.w);
    ((ushort4*)dst)[i] = o;
}

// W (K x N fp32) -> WT (N x K bf16)
__global__ __launch_bounds__(256) void transpose_cvt(
    const float* __restrict__ W, ushort_t* __restrict__ WT, int K, int N) {
    __shared__ float t[32][33];
    const int tx = threadIdx.x & 31, ty = threadIdx.x >> 5;
    const int n0 = blockIdx.x * 32, k0 = blockIdx.y * 32;
#pragma unroll
    for (int i = 0; i < 4; ++i)
        t[ty + 8 * i][tx] = W[(size_t)(k0 + ty + 8 * i) * N + n0 + tx];
    __syncthreads();
#pragma unroll
    for (int i = 0; i < 4; ++i)
        WT[(size_t)(n0 + ty + 8 * i) * K + k0 + tx] = f2bf(t[tx][ty + 8 * i]);
}

// ------------------------------ MFMA GEMM ----------------------------------
// C = A(M x K, bf16 row-major) @ BT(N x K, bf16 row-major)^T.
// MODE 0: out bf16 g-chunk (M x 3*CW), tanh (gate 0) / sigmoid (gates 1,2).
// MODE 1: FC, fp32 out, bias only. 256 thr = 4 waves, tile 128x128, BK=64.
template <int MODE>
__global__ __launch_bounds__(256) void gemm_mfma(
    const ushort_t* __restrict__ A, const ushort_t* __restrict__ BT,
    const float* __restrict__ bias, void* __restrict__ out,
    int K, int c0, int CW) {
    __shared__ ushort_t As[128 * 64];
    __shared__ ushort_t Bs[128 * 64];

    const int tid = threadIdx.x;
    const int lane = tid & 63;
    const int w = tid >> 6;
    const int wr = w >> 1, wc = w & 1;
    const int m0 = blockIdx.y * 128;

    int nW, nOut, outstride, gate = 0;
    if (MODE == 0) {
        const int per = CW >> 7;
        gate = blockIdx.x / per;
        const int nloc = (blockIdx.x - gate * per) * 128;
        nW = gate * QH + c0 + nloc;
        nOut = gate * CW + nloc;
        outstride = 3 * CW;
    } else {
        nW = blockIdx.x * 128;
        nOut = nW;
        outstride = QOUT;
    }

    size_t aoff[4], boff[4];
    int soff[4];
#pragma unroll
    for (int j = 0; j < 4; ++j) {
        const int s = ((w * 4 + j) << 6) + lane;
        const int ms = s >> 3;
        const int kg = (s & 7) ^ (ms & 7);
        aoff[j] = (size_t)(m0 + ms) * K + kg * 8;
        boff[j] = (size_t)(nW + ms) * K + kg * 8;
        soff[j] = (w * 4 + j) << 9;
    }

    const int fl = lane & 15, fq = lane >> 4, l7 = lane & 7;
    int aidx[2][4], bidx[2][4];
#pragma unroll
    for (int ks = 0; ks < 2; ++ks)
#pragma unroll
        for (int i = 0; i < 4; ++i) {
            const int am = wr * 64 + i * 16 + fl;
            const int bn = wc * 64 + i * 16 + fl;
            const int kq = ks * 4 + fq;
            aidx[ks][i] = (am * 8 + (kq ^ l7)) * 8;
            bidx[ks][i] = (bn * 8 + (kq ^ l7)) * 8;
        }

    f32x4 acc[4][4];
#pragma unroll
    for (int i = 0; i < 4; ++i)
#pragma unroll
        for (int j = 0; j < 4; ++j) acc[i][j] = {0.f, 0.f, 0.f, 0.f};

    for (int k0 = 0; k0 < K; k0 += 64) {
        __syncthreads();
#pragma unroll
        for (int j = 0; j < 4; ++j) glds16(A + aoff[j] + k0, &As[soff[j]]);
#pragma unroll
        for (int j = 0; j < 4; ++j) glds16(BT + boff[j] + k0, &Bs[soff[j]]);
        __syncthreads();
#pragma unroll
        for (int ks = 0; ks < 2; ++ks) {
            bf16x8 af[4], bv[4];
#pragma unroll
            for (int i = 0; i < 4; ++i)
                af[i] = *(const bf16x8*)&As[aidx[ks][i]];
#pragma unroll
            for (int j = 0; j < 4; ++j)
                bv[j] = *(const bf16x8*)&Bs[bidx[ks][j]];
#pragma unroll
            for (int i = 0; i < 4; ++i)
#pragma unroll
                for (int j = 0; j < 4; ++j)
                    acc[i][j] = __builtin_amdgcn_mfma_f32_16x16x32_bf16(
                        af[i], bv[j], acc[i][j], 0, 0, 0);
        }
    }

    // Epilogue. C/D: col = lane&15, row = (lane>>4)*4 + reg.
    const int rbase = fq * 4;
#pragma unroll
    for (int i = 0; i < 4; ++i) {
#pragma unroll
        for (int j = 0; j < 4; ++j) {
            const int col = nOut + wc * 64 + j * 16 + fl;
            const float bvv = bias[nW + wc * 64 + j * 16 + fl];
            const int row0 = m0 + wr * 64 + i * 16 + rbase;
#pragma unroll
            for (int r = 0; r < 4; ++r) {
                float v = acc[i][j][r] + bvv;
                if (MODE == 0) {
                    v = (gate == 0) ? tanhf(v) : 1.f / (1.f + expf(-v));
                    ((ushort_t*)out)[(size_t)(row0 + r) * outstride + col] =
                        f2bf(v);
                } else {
                    ((float*)out)[(size_t)(row0 + r) * outstride + col] = v;
                }
            }
        }
    }
}

// ----------------------- segmented fo-scan (3 passes) ----------------------
// g: (T, B, 3, CW) bf16 activated z,f,o. c = f*c + (1-f)*z as (A,B) pairs.

// Pass 1: per-(seg,b,hh) summary. idx = (s*QB + b)*CW + hh.
__global__ __launch_bounds__(256) void scan_p1(const ushort_t* __restrict__ g,
                                               float* __restrict__ Aseg,
                                               float* __restrict__ Bseg,
                                               int CW) {
    const int idx = blockIdx.x * 256 + threadIdx.x;
    const int hh = idx % CW;
    const int sb = idx / CW;
    const int b = sb % QB;
    const int s = sb / QB;
    const ushort_t* gp = g + ((size_t)(s * SL * QB + b) * 3) * CW + hh;
    const size_t grow = (size_t)QB * 3 * CW;
    float zv[SL], fv[SL];
#pragma unroll
    for (int t = 0; t < SL; ++t) {
        zv[t] = u2f(gp[0]);
        fv[t] = u2f(gp[CW]);
        gp += grow;
    }
    float A = 1.f, Bc = 0.f;
#pragma unroll
    for (int t = 0; t < SL; ++t) {
        Bc = fv[t] * Bc + (1.f - fv[t]) * zv[t];
        A *= fv[t];
    }
    Aseg[idx] = A;
    Bseg[idx] = Bc;
}

// Pass 2: scan SEG summaries; prefetch all pairs then register chain.
__global__ __launch_bounds__(256) void scan_p2(const float* __restrict__ Aseg,
                                               const float* __restrict__ Bseg,
                                               float* __restrict__ cstart,
                                               int CW) {
    const int idx = blockIdx.x * 256 + threadIdx.x;
    const size_t stride = (size_t)QB * CW;
    float Av[SEG], Bv[SEG];
#pragma unroll
    for (int s = 0; s < SEG; ++s) {
        Av[s] = Aseg[s * stride + idx];
        Bv[s] = Bseg[s * stride + idx];
    }
    float c = 0.f;
#pragma unroll
    for (int s = 0; s < SEG; ++s) {
        cstart[s * stride + idx] = c;
        c = Av[s] * c + Bv[s];
    }
}

// Pass 3: recompute interior states, write h (bf16).
__global__ __launch_bounds__(256) void scan_p3(const ushort_t* __restrict__ g,
                                               const float* __restrict__ cstart,
                                               ushort_t* __restrict__ h,
                                               int c0, int CW) {
    const int idx = blockIdx.x * 256 + threadIdx.x;
    const int hh = idx % CW;
    const int sb = idx / CW;
    const int b = sb % QB;
    const int s = sb / QB;
    const ushort_t* gp = g + ((size_t)(s * SL * QB + b) * 3) * CW + hh;
    ushort_t* hp = h + (size_t)(s * SL * QB + b) * QH + c0 + hh;
    const size_t grow = (size_t)QB * 3 * CW;
    const size_t hrow = (size_t)QB * QH;
    float zv[SL], fv[SL], ov[SL];
#pragma unroll
    for (int t = 0; t < SL; ++t) {
        zv[t] = u2f(gp[0]);
        fv[t] = u2f(gp[CW]);
        ov[t] = u2f(gp[2 * CW]);
        gp += grow;
    }
    float c = cstart[idx];
#pragma unroll
    for (int t = 0; t < SL; ++t) {
        c = fv[t] * c + (1.f - fv[t]) * zv[t];
        *hp = f2bf(ov[t] * c);
        hp += hrow;
    }
}

extern "C" void kernel_launch(void* const* d_in, const int* in_sizes, int n_in,
                              void* d_out, int out_size, void* d_ws,
                              size_t ws_size, hipStream_t stream) {
    const float* x   = (const float*)d_in[0];
    const float* W0  = (const float*)d_in[1];
    const float* b0  = (const float*)d_in[2];
    const float* W1  = (const float*)d_in[3];
    const float* b1  = (const float*)d_in[4];
    const float* Wfc = (const float*)d_in[5];
    const float* bfc = (const float*)d_in[6];
    float* out = (float*)d_out;

    char* p = (char*)d_ws;
    ushort_t* h0   = (ushort_t*)p;  p += (size_t)QM * QH * 2;
    ushort_t* h1   = (ushort_t*)p;  // x_bf aliases h1 (dead before h1 write)
    ushort_t* x_bf = (ushort_t*)p;  p += (size_t)QM * QH * 2;
    ushort_t* W0T  = (ushort_t*)p;  p += (size_t)3 * QH * QIN * 2;
    ushort_t* W1T  = (ushort_t*)p;  p += (size_t)3 * QH * QH * 2;
    ushort_t* WfcT = (ushort_t*)p;  p += (size_t)QOUT * QH * 2;
    const size_t base = (size_t)(p - (char*)d_ws);

    // Largest CW (>=128) fitting: base + 3 summary arrays + bf16 g-chunk.
    int CW = QH;
    while (CW > 128 &&
           base + 3 * (size_t)QB * CW * SEG * 4 + (size_t)QM * 3 * CW * 2 >
               ws_size)
        CW >>= 1;
    const int nch = QH / CW;

    float* Aseg   = (float*)p;  p += (size_t)QB * CW * SEG * 4;
    float* Bseg   = (float*)p;  p += (size_t)QB * CW * SEG * 4;
    float* cstart = (float*)p;  p += (size_t)QB * CW * SEG * 4;
    ushort_t* g   = (ushort_t*)p;

    dim3 blk(256);

    cvt_bf16<<<dim3(QM * QIN / 1024), blk, 0, stream>>>(x, x_bf);
    transpose_cvt<<<dim3(3 * QH / 32, QIN / 32), blk, 0, stream>>>(
        W0, W0T, QIN, 3 * QH);
    transpose_cvt<<<dim3(3 * QH / 32, QH / 32), blk, 0, stream>>>(
        W1, W1T, QH, 3 * QH);
    transpose_cvt<<<dim3(QOUT / 32, QH / 32), blk, 0, stream>>>(
        Wfc, WfcT, QH, QOUT);

    const dim3 ggrid(3 * (CW >> 7), QM / 128);
    const dim3 p13grid(SEG * QB * CW / 256);
    const dim3 p2grid(QB * CW / 256);

    for (int ci = 0; ci < nch; ++ci) {
        gemm_mfma<0><<<ggrid, blk, 0, stream>>>(x_bf, W0T, b0, g, QIN,
                                                ci * CW, CW);
        scan_p1<<<p13grid, blk, 0, stream>>>(g, Aseg, Bseg, CW);
        scan_p2<<<p2grid, blk, 0, stream>>>(Aseg, Bseg, cstart, CW);
        scan_p3<<<p13grid, blk, 0, stream>>>(g, cstart, h0, ci * CW, CW);
    }
    for (int ci = 0; ci < nch; ++ci) {
        gemm_mfma<0><<<ggrid, blk, 0, stream>>>(h0, W1T, b1, g, QH,
                                                ci * CW, CW);
        scan_p1<<<p13grid, blk, 0, stream>>>(g, Aseg, Bseg, CW);
        scan_p2<<<p2grid, blk, 0, stream>>>(Aseg, Bseg, cstart, CW);
        scan_p3<<<p13grid, blk, 0, stream>>>(g, cstart, h1, ci * CW, CW);
    }
    gemm_mfma<1><<<dim3(QOUT / 128, QM / 128), blk, 0, stream>>>(
        h1, WfcT, bfc, out, QH, 0, 0);
}